// Round 11
// baseline (166.447 us; speedup 1.0000x reference)
//
#include <hip/hip_runtime.h>
#include <hip/hip_bf16.h>
#include <stdint.h>

typedef __bf16 bf16_t;
typedef bf16_t bf16x4 __attribute__((ext_vector_type(4)));
typedef bf16_t bf16x8 __attribute__((ext_vector_type(8)));
typedef float  f32x4  __attribute__((ext_vector_type(4)));
typedef float  f32x16 __attribute__((ext_vector_type(16)));

#define GAS __attribute__((address_space(1)))
#define LAS __attribute__((address_space(3)))

__device__ inline void gld_lds16(const void* g, void* l) {
    __builtin_amdgcn_global_load_lds((const GAS void*)g, (LAS void*)l, 16, 0, 0);
}

// byte offset into a [rows][64] bf16 tile (128B rows), XOR-swizzled (T2)
__device__ inline int swz(int row, int colbyte) {
    return row * 128 + (colbyte ^ ((row & 7) << 4));
}

// ---------------- fp32 -> bf16 convert, all 5 tensors in one launch ----------------
__global__ __launch_bounds__(256) void k_cvt5(const float* __restrict__ i0, bf16_t* __restrict__ o0,
                                              const float* __restrict__ i1, bf16_t* __restrict__ o1,
                                              const float* __restrict__ i2, bf16_t* __restrict__ o2,
                                              const float* __restrict__ i3, bf16_t* __restrict__ o3,
                                              const float* __restrict__ i4, bf16_t* __restrict__ o4) {
    const float* in; bf16_t* out; int n;
    switch (blockIdx.y) {
        case 0: in = i0; out = o0; n = 4194304; break;
        case 1: in = i1; out = o1; n = 1048576; break;
        case 2: in = i2; out = o2; n = 1048576; break;
        case 3: in = i3; out = o3; n = 1048576; break;
        default: in = i4; out = o4; n = 1048576; break;
    }
    int i = (blockIdx.x * 256 + threadIdx.x) * 8;
    if (i >= n) return;
    f32x4 v0 = *(const f32x4*)(in + i);
    f32x4 v1 = *(const f32x4*)(in + i + 4);
    bf16x8 o;
    o[0] = (bf16_t)v0[0]; o[1] = (bf16_t)v0[1]; o[2] = (bf16_t)v0[2]; o[3] = (bf16_t)v0[3];
    o[4] = (bf16_t)v1[0]; o[5] = (bf16_t)v1[1]; o[6] = (bf16_t)v1[2]; o[7] = (bf16_t)v1[3];
    *(bf16x8*)(out + i) = o;
}

// ---------------- RoPE on bf16 [4096][1024], pairs along head-dim ----------------
__global__ __launch_bounds__(256) void k_rope(bf16_t* __restrict__ Q, bf16_t* __restrict__ Kt,
                                              const float* __restrict__ sn,
                                              const float* __restrict__ cs) {
    int idx = blockIdx.x * 256 + threadIdx.x;   // pair index, total 4096*512
    bf16_t* T = blockIdx.y ? Kt : Q;
    int row = idx >> 9;          // 0..4095
    int pi  = idx & 511;
    int h = pi >> 5, i = pi & 31;
    int p = row & 2047;
    float c = cs[p * 32 + i], s = sn[p * 32 + i];
    bf16_t* ptr = T + (size_t)row * 1024 + h * 64 + 2 * i;
    float e = (float)ptr[0], o = (float)ptr[1];
    ptr[0] = (bf16_t)(e * c - o * s);
    ptr[1] = (bf16_t)(e * s + o * c);
}

// ---------------- GEMM  C[M][N] = A[M][K] * B[N][K]^T  (bf16 in, OutT out) ----------------
template <typename OutT>
__global__ __launch_bounds__(256) void k_gemm_bt(
    const bf16_t* __restrict__ A,
    const bf16_t* __restrict__ B0, const bf16_t* __restrict__ B1,
    OutT* __restrict__ C0, OutT* __restrict__ C1,
    int M, int N, int K) {
    const bf16_t* B = blockIdx.z == 0 ? B0 : B1;
    OutT*         C = blockIdx.z == 0 ? C0 : C1;
    const int BK = 32;
    __shared__ bf16_t As[128 * BK];
    __shared__ bf16_t Bs[128 * BK];
    int tid = threadIdx.x;
    int lane = tid & 63, wid = tid >> 6;
    int row0 = blockIdx.y * 128, col0 = blockIdx.x * 128;
    int wr = (wid >> 1) * 64, wc = (wid & 1) * 64;
    int lr = lane & 15, kg = lane >> 4;

    f32x4 acc[4][4];
#pragma unroll
    for (int i = 0; i < 4; ++i)
#pragma unroll
        for (int j = 0; j < 4; ++j) acc[i][j] = (f32x4){0.f, 0.f, 0.f, 0.f};

    int ob = tid * 16;  // byte offset within a 4096-byte staging pass
    for (int k0 = 0; k0 < K; k0 += BK) {
        __syncthreads();
#pragma unroll
        for (int p = 0; p < 2; ++p) {
            int off = p * 4096 + ob;
            int r = off >> 6;      // 64 bytes per 32-elem row
            int cb = off & 63;
            gld_lds16((const char*)A + ((size_t)(row0 + r) * K + k0) * 2 + cb, (char*)As + off);
            gld_lds16((const char*)B + ((size_t)(col0 + r) * K + k0) * 2 + cb, (char*)Bs + off);
        }
        __syncthreads();
        bf16x8 af[4], bfr[4];
#pragma unroll
        for (int mi = 0; mi < 4; ++mi)
            af[mi] = *(const bf16x8*)&As[(wr + mi * 16 + lr) * BK + kg * 8];
#pragma unroll
        for (int ni = 0; ni < 4; ++ni)
            bfr[ni] = *(const bf16x8*)&Bs[(wc + ni * 16 + lr) * BK + kg * 8];
#pragma unroll
        for (int mi = 0; mi < 4; ++mi)
#pragma unroll
            for (int ni = 0; ni < 4; ++ni)
                acc[mi][ni] = __builtin_amdgcn_mfma_f32_16x16x32_bf16(af[mi], bfr[ni],
                                                                      acc[mi][ni], 0, 0, 0);
    }
#pragma unroll
    for (int mi = 0; mi < 4; ++mi)
#pragma unroll
        for (int ni = 0; ni < 4; ++ni)
#pragma unroll
            for (int r = 0; r < 4; ++r) {
                int row = row0 + wr + mi * 16 + kg * 4 + r;
                int col = col0 + wc + ni * 16 + lr;
                C[(size_t)row * N + col] = (OutT)acc[mi][ni][r];
            }
}

// ---------------- Flash attention: 32x32 MFMA, in-register softmax, P via LDS ----------------
// grid (16, 16, 2) x 256 threads; one 32-q-row strip per wave (duration-uniform map).
// S^T = mfma_32x32x16(K,Q): lane owns q = lane&31, 32 of 64 k-values in regs
// (other half on lane^32). Softmax: in-reg tree + __shfl_xor(,32) folds (2 ds ops).
// P routed [q][k] through private swizzled LDS: sa[t][g*4..+3] are 4 CONSECUTIVE k
// -> 8x ds_write_b64 + 4x ds_read_b128 per step (vs 28 ds ops in the 16x16 version).
__global__ __launch_bounds__(256, 2) void k_flash(const bf16_t* __restrict__ Q,
                                                  const bf16_t* __restrict__ K,
                                                  const bf16_t* __restrict__ Vt,
                                                  bf16_t* __restrict__ Ob) {
    const int DM = 1024, S = 2048, NB = 4096;
    int h = blockIdx.y, b = blockIdx.z;
    int tid = threadIdx.x, lane = tid & 63, wid = tid >> 6;
    int ql = lane & 31, hi = lane >> 5;
    int rowbase = b * S;
    int colbase = h * 64;
    int quad = b ? (15 - (int)blockIdx.x) : (int)blockIdx.x;
    int s = quad * 4 + wid;          // strip 0..63 within (h,b)
    int spos = s * 32;
    int kbmax = s >> 1;
    int q = spos + ql;               // this lane's q row

    __shared__ bf16_t Ps[4][32 * 64];
    char* Pw = (char*)&Ps[wid][0];

    const bf16_t* Kg = K + (size_t)rowbase * DM + colbase;   // [k][d]
    const bf16_t* Vg = Vt + (size_t)colbase * NB + rowbase;  // [d][k]

    // A-operand K fragments: kf[t*4+c] = K[kb*64 + t*32 + ql][c*16 + hi*8 ..+7]
#define LOADK(kb, dst)                                                               \
    _Pragma("unroll") for (int t = 0; t < 2; ++t)                                    \
    _Pragma("unroll") for (int c = 0; c < 4; ++c)                                    \
        dst[t * 4 + c] = *(const bf16x8*)&Kg[(size_t)((kb) * 64 + t * 32 + ql) * DM  \
                                             + c * 16 + hi * 8];

    // A-operand V^T fragments: vf[od*4+kc] = Vt[od*32 + ql][kb*64 + kc*16 + hi*8 ..+7]
#define LOADV(kb, dst)                                                               \
    _Pragma("unroll") for (int od = 0; od < 2; ++od)                                 \
    _Pragma("unroll") for (int kc = 0; kc < 4; ++kc)                                 \
        dst[od * 4 + kc] = *(const bf16x8*)&Vg[(size_t)(od * 32 + ql) * NB           \
                                               + (kb) * 64 + kc * 16 + hi * 8];

    // B-operand Q fragments: qf[c] = Q[spos + ql][c*16 + hi*8 ..+7]
    bf16x8 qf[4];
#pragma unroll
    for (int c = 0; c < 4; ++c)
        qf[c] = *(const bf16x8*)&Q[(size_t)(rowbase + spos + ql) * DM + colbase +
                                   c * 16 + hi * 8];

    f32x16 Oa[2];     // O^T[d = od*32 + (reg&3)+8*(reg>>2)+4*hi][q = ql]
#pragma unroll
    for (int od = 0; od < 2; ++od)
#pragma unroll
        for (int r = 0; r < 16; ++r) Oa[od][r] = 0.f;
    float m_run = -1e30f, l_run = 0.f;

    bf16x8 kf[8], vf[8];
    LOADK(0, kf);
    LOADV(0, vf);

#pragma unroll 1
    for (int kb = 0; kb <= kbmax; ++kb) {
        // ---- S^T[k][q] : sa[t][g*4+j] = S[q=ql][k = kb*64 + t*32 + g*8 + 4*hi + j]
        f32x16 sa[2];
#pragma unroll
        for (int t = 0; t < 2; ++t)
#pragma unroll
            for (int r = 0; r < 16; ++r) sa[t][r] = 0.f;
        __builtin_amdgcn_s_setprio(1);
#pragma unroll
        for (int t = 0; t < 2; ++t)
#pragma unroll
            for (int c = 0; c < 4; ++c)
                sa[t] = __builtin_amdgcn_mfma_f32_32x32x16_bf16(kf[t * 4 + c], qf[c],
                                                                sa[t], 0, 0, 0);
        __builtin_amdgcn_s_setprio(0);

        bool pre = kb < kbmax;
        if (pre) { LOADK(kb + 1, kf); }   // prefetch hides under softmax+PV

        if (kb == kbmax) {   // causal mask, diagonal tile only
#pragma unroll
            for (int t = 0; t < 2; ++t)
#pragma unroll
                for (int g = 0; g < 4; ++g)
#pragma unroll
                    for (int j = 0; j < 4; ++j)
                        if (kb * 64 + t * 32 + g * 8 + 4 * hi + j > q)
                            sa[t][g * 4 + j] = -1e30f;
        }

        // ---- online softmax, lane owns one q; cross-half fold via shfl_xor(32) ----
        float mx = -1e30f;
#pragma unroll
        for (int t = 0; t < 2; ++t)
#pragma unroll
            for (int r = 0; r < 16; ++r) mx = fmaxf(mx, sa[t][r]);
        mx = fmaxf(mx, __shfl_xor(mx, 32));
        float mn = fmaxf(m_run, mx);
        float sc = __expf(m_run - mn);
        m_run = mn;
        float rs = 0.f;
#pragma unroll
        for (int t = 0; t < 2; ++t)
#pragma unroll
            for (int r = 0; r < 16; ++r) {
                float pv = __expf(sa[t][r] - mn);
                sa[t][r] = pv;
                rs += pv;
            }
        rs += __shfl_xor(rs, 32);
        l_run = l_run * sc + rs;
#pragma unroll
        for (int od = 0; od < 2; ++od)
#pragma unroll
            for (int r = 0; r < 16; ++r) Oa[od][r] *= sc;

        // ---- P -> LDS: sa[t][g*4..+3] = 4 consecutive k at k0 = t*32+g*8+4*hi ----
#pragma unroll
        for (int t = 0; t < 2; ++t)
#pragma unroll
            for (int g = 0; g < 4; ++g) {
                bf16x4 pk;
#pragma unroll
                for (int j = 0; j < 4; ++j) pk[j] = (bf16_t)sa[t][g * 4 + j];
                *(bf16x4*)(Pw + swz(ql, (t * 32 + g * 8 + 4 * hi) * 2)) = pk;
            }

        // ---- O^T += V^T * P^T : pf[kc][j] = P[q=ql][k = kc*16 + hi*8 + j] ----
#pragma unroll
        for (int kc = 0; kc < 4; ++kc) {
            bf16x8 pf = *(const bf16x8*)(Pw + swz(ql, kc * 32 + hi * 16));
            __builtin_amdgcn_s_setprio(1);
#pragma unroll
            for (int od = 0; od < 2; ++od)
                Oa[od] = __builtin_amdgcn_mfma_f32_32x32x16_bf16(vf[od * 4 + kc], pf,
                                                                 Oa[od], 0, 0, 0);
            __builtin_amdgcn_s_setprio(0);
        }

        if (pre) { LOADV(kb + 1, vf); }   // prefetch across step boundary
    }

    // ---- epilogue: O[q][d] = O^T[d][q] / l ----
    float inv = 1.f / l_run;
    size_t row = (size_t)(rowbase + spos + ql);
#pragma unroll
    for (int od = 0; od < 2; ++od)
#pragma unroll
        for (int g = 0; g < 4; ++g) {
            bf16x4 o;
#pragma unroll
            for (int j = 0; j < 4; ++j) o[j] = (bf16_t)(Oa[od][g * 4 + j] * inv);
            *(bf16x4*)&Ob[row * DM + colbase + od * 32 + g * 8 + 4 * hi] = o;
        }
#undef LOADK
#undef LOADV
}

extern "C" void kernel_launch(void* const* d_in, const int* in_sizes, int n_in,
                              void* d_out, int out_size, void* d_ws, size_t ws_size,
                              hipStream_t stream) {
    const float* x  = (const float*)d_in[0];
    const float* wk = (const float*)d_in[1];  // key_weight
    const float* wq = (const float*)d_in[2];  // query_weight
    const float* wv = (const float*)d_in[3];  // value_weight
    const float* wo = (const float*)d_in[4];  // output_weight
    const float* sn = (const float*)d_in[5];
    const float* cs = (const float*)d_in[6];
    float* out = (float*)d_out;
    (void)in_sizes; (void)n_in; (void)out_size; (void)ws_size;

    char* ws = (char*)d_ws;
    const size_t MB = 1024 * 1024;
    bf16_t* xb  = (bf16_t*)(ws + 0);        // 4096x1024
    bf16_t* wqb = (bf16_t*)(ws + 8 * MB);   // 1024x1024
    bf16_t* wkb = (bf16_t*)(ws + 10 * MB);
    bf16_t* wvb = (bf16_t*)(ws + 12 * MB);
    bf16_t* wob = (bf16_t*)(ws + 14 * MB);
    bf16_t* Qb  = (bf16_t*)(ws + 16 * MB);  // 4096x1024
    bf16_t* Kb  = (bf16_t*)(ws + 24 * MB);  // 4096x1024
    bf16_t* Vtb = (bf16_t*)(ws + 32 * MB);  // 1024x4096 (V^T: [h*64+d][b*2048+s])
    bf16_t* Ob  = (bf16_t*)(ws + 40 * MB);  // 4096x1024

    k_cvt5<<<dim3(2048, 5), 256, 0, stream>>>(x, xb, wq, wqb, wk, wkb, wv, wvb, wo, wob);

    // Q/K projections: C[bp][h*64+d] = sum_m x[bp][m] * W[h*64+d][m]
    k_gemm_bt<bf16_t><<<dim3(8, 32, 2), 256, 0, stream>>>(
        xb, wqb, wkb, Qb, Kb, 4096, 1024, 1024);
    // V projection, output-transposed: Vt[h*64+d][b*2048+s] = sum_m Wv[hd][m] x[bs][m]
    k_gemm_bt<bf16_t><<<dim3(32, 8, 1), 256, 0, stream>>>(
        wvb, xb, xb, Vtb, Vtb, 1024, 4096, 1024);

    k_rope<<<dim3(8192, 2), 256, 0, stream>>>(Qb, Kb, sn, cs);

    k_flash<<<dim3(16, 16, 2), 256, 0, stream>>>(Qb, Kb, Vtb, Ob);

    // out[bp][m] = sum_hd Ob[bp][hd] * wo[m][hd]
    k_gemm_bt<float><<<dim3(8, 32, 1), 256, 0, stream>>>(
        Ob, wob, wob, out, out, 4096, 1024, 1024);
}